// Round 3
// baseline (124.561 us; speedup 1.0000x reference)
//
#include <hip/hip_runtime.h>

// LengthRegulator fused: B=32, T=256, D=384, MAX_LEN=2048
// out[b,f,:] = x[b, searchsorted(csum[b], f, 'right'), :] if f < mel_len[b] else 0
// mel_len[b] = csum[b, T-1]
//
// Single kernel: each block owns FPB frames of one batch, recomputes the
// 256-token csum in-block (shfl scan, ~100 cyc), scatters frame->token idx
// into LDS (O(1) per token, replaces 8-deep binary search), then streams
// fully-coalesced nontemporal float4 writes.

#define BB 32
#define TT 256
#define DD 384
#define MAXLEN 2048
#define D4 (DD / 4)            // 96 float4 per frame
#define FPB 16                 // frames per block
#define TILES (MAXLEN / FPB)   // 128 tiles per batch

typedef float v4f __attribute__((ext_vector_type(4)));  // clang vector: valid for nontemporal builtins

__global__ __launch_bounds__(256) void lr_fused(const float* __restrict__ x,
                                                const int* __restrict__ duration,
                                                float* __restrict__ out,
                                                float* __restrict__ mel_out) {
    __shared__ int s_csum[TT];
    __shared__ int s_wsum[4];
    __shared__ int s_idx[FPB];

    const int bid = blockIdx.x;
    const int b = bid >> 7;            // bid / TILES (TILES == 128)
    const int tile = bid & (TILES - 1);
    const int tid = threadIdx.x;
    const int lane = tid & 63;
    const int wave = tid >> 6;

    // ---- in-block inclusive scan of this batch's duration row ----
    const int d = duration[b * TT + tid];
    int v = d;
    #pragma unroll
    for (int off = 1; off < 64; off <<= 1) {
        int n = __shfl_up(v, off, 64);
        if (lane >= off) v += n;
    }
    if (lane == 63) s_wsum[wave] = v;
    if (tid < FPB) s_idx[tid] = -1;    // -1 => invalid frame => zeros
    __syncthreads();
    int prefix = 0;
    #pragma unroll
    for (int w = 0; w < 4; ++w) prefix += (w < wave) ? s_wsum[w] : 0;
    const int cend = v + prefix;       // csum[b][tid] (inclusive)
    s_csum[tid] = cend;
    __syncthreads();

    const int mel = s_csum[TT - 1];
    if (tile == 0 && tid == 0) mel_out[b] = (float)mel;  // output 1 (fp32 buffer)

    // ---- scatter: token tid covers frames [cend-d, cend) ----
    // For any covered frame f this equals searchsorted(csum, f, 'right'):
    // csum[tid] > f and csum[tid-1] <= f; zero-duration tokens cover nothing.
    const int base = tile * FPB;
    {
        const int cstart = cend - d;
        int lo = cstart > base ? cstart : base;
        int hi = cend < base + FPB ? cend : base + FPB;
        for (int f = lo; f < hi; ++f) s_idx[f - base] = tid;
    }
    __syncthreads();

    // ---- stream: FPB*D4 = 1536 float4 per block, 6 coalesced iterations ----
    const v4f* __restrict__ x4 = (const v4f*)(x + (size_t)b * TT * DD);
    v4f* __restrict__ o4 = (v4f*)(out + ((size_t)b * MAXLEN + base) * DD);

    #pragma unroll
    for (int i = 0; i < (FPB * D4) / 256; ++i) {
        const int g = i * 256 + tid;
        const int fl = g / D4;          // frame within tile (const-div -> magic mul)
        const int vv = g - fl * D4;     // float4 column
        const int idx = s_idx[fl];
        v4f val = (v4f)(0.f);
        if (idx >= 0) val = x4[idx * D4 + vv];
        __builtin_nontemporal_store(val, &o4[g]);   // write-once output: skip L2 reuse
    }
}

extern "C" void kernel_launch(void* const* d_in, const int* in_sizes, int n_in,
                              void* d_out, int out_size, void* d_ws, size_t ws_size,
                              hipStream_t stream) {
    const float* x = (const float*)d_in[0];
    const int* duration = (const int*)d_in[1];
    // d_in[2] = max_len (constant 2048)

    float* out = (float*)d_out;                       // [B, MAXLEN, D] fp32
    float* mel_out = out + (size_t)BB * MAXLEN * DD;  // [B] mel_len as float

    lr_fused<<<BB * TILES, 256, 0, stream>>>(x, duration, out, mel_out);
}